// Round 4
// baseline (389.216 us; speedup 1.0000x reference)
//
#include <hip/hip_runtime.h>
#include <math.h>

#define NROWS 500000
#define NGRP  50000
#define NEG   0.2f
#define GPB   32          // groups per block

__device__ __forceinline__ float leaky(float h) { return h >= 0.f ? h : NEG * h; }

// ---------------------------------------------------------------------------
// K0: Wsum = W1a + W1B + W1c  (row-major [k][j], 64x64) -> ws
__global__ void k0_wsum(const float* __restrict__ w1, float* __restrict__ wsum) {
    int i = blockIdx.x * 256 + threadIdx.x;
    if (i < 4096) wsum[i] = w1[i] + w1[4096 + i] + w1[8192 + i];
}

// ---------------------------------------------------------------------------
// Fused kernel. Block = 32 consecutive CSR groups (~320 rows avg).
// Phase A1: per-group min/max (wave-serial, lane = feature dim) -> LDS.
// Phase A2: bias_g = -(mn@W1b + mx@W1c), batched GEMV: lane = group,
//           j split across 4 waves (jb in SGPR -> weight rows s_load).
// Phase B : 64-row chunks through the 2-layer MLP (k2 structure):
//           lane = row, 16 acc per wave, s_load weights, LDS transpose
//           epilogue for coalesced float4 stores.
// x's second read (phase B) is L2-hot from phase A -> HBM traffic = x + out.
__global__ __launch_bounds__(256)
void fused(const float* __restrict__ x, const int* __restrict__ csr,
           const float* __restrict__ w1, const float* __restrict__ wsum,
           const float* __restrict__ w2, float* __restrict__ out) {
    __shared__ float smem[64 * 65];    // A: mnmx[32][129] (4128f)  B: xtile[64][65]
    __shared__ float biasL[GPB * 65];  // per-group bias, stride 65 (bank-friendly)
    __shared__ int   csrl[GPB + 1];

    const int tid  = threadIdx.x;
    const int w    = tid >> 6;
    const int lane = tid & 63;
    // wave-uniform j-offset in SGPR => weight-row reads scalar-promote (s_load)
    const int jb   = __builtin_amdgcn_readfirstlane(w * 16);

    const int g0 = blockIdx.x * GPB;
    const int ng = min(GPB, NGRP - g0);

    if (tid <= ng) csrl[tid] = csr[g0 + tid];
    __syncthreads();
    const int p0 = csrl[0], p1 = csrl[ng];

    // ---- Phase A1: min/max per group; wave w handles local groups w, w+4, ...
    for (int gl = w; gl < ng; gl += 4) {
        const int q0 = csrl[gl], q1 = csrl[gl + 1];
        const int cnt = q1 - q0;
        if (cnt > 0) {
            const float* p = x + (size_t)q0 * 64 + lane;
            float mn = INFINITY, mx = -INFINITY;
            int i = 0;
            for (; i + 4 <= cnt; i += 4) {
                float a = p[0], b = p[64], c = p[128], d = p[192];
                p += 256;
                mn = fminf(mn, fminf(fminf(a, b), fminf(c, d)));
                mx = fmaxf(mx, fmaxf(fmaxf(a, b), fmaxf(c, d)));
            }
            for (; i < cnt; ++i) { float a = p[0]; p += 64; mn = fminf(mn, a); mx = fmaxf(mx, a); }
            smem[gl * 129 + lane]      = mn;
            smem[gl * 129 + 64 + lane] = mx;
        }
    }
    __syncthreads();

    // ---- Phase A2: bias GEMV. lane = local group (clamped for OOB-safety).
    {
        const int gidx = lane < GPB ? lane : GPB - 1;   // keep ds_read in bounds
        float acc[16];
#pragma unroll
        for (int j = 0; j < 16; ++j) acc[j] = 0.f;
#pragma unroll 2
        for (int k = 0; k < 128; ++k) {
            float m = smem[gidx * 129 + k];             // mn (k<64) / mx (k>=64)
            const float* __restrict__ wr = w1 + (64 + k) * 64 + jb;  // s_load
#pragma unroll
            for (int j = 0; j < 16; ++j) acc[j] = fmaf(m, wr[j], acc[j]);
        }
        if (lane < ng) {
#pragma unroll
            for (int j = 0; j < 16; ++j) biasL[lane * 65 + jb + j] = -acc[j];
        }
    }
    __syncthreads();  // bias ready; smem now free for x tiles

    // ---- Phase B: 64-row chunks
    const int nch = (p1 - p0 + 63) >> 6;
    for (int ch = 0; ch < nch; ++ch) {
        const int r0c  = p0 + (ch << 6);
        const int rows = min(64, p1 - r0c);
        const int availf = rows * 64;

        // stage x chunk (coalesced float4; 256B-aligned since offset is k*64 floats)
        const float4* x4 = (const float4*)(x + (size_t)r0c * 64);
#pragma unroll
        for (int i = 0; i < 4; ++i) {
            int f = (i * 256 + tid) * 4;
            if (f < availf) {
                float4 v = x4[f >> 2];
                int r = f >> 6, c = f & 63;
                smem[r * 65 + c]     = v.x; smem[r * 65 + c + 1] = v.y;
                smem[r * 65 + c + 2] = v.z; smem[r * 65 + c + 3] = v.w;
            }
        }
        __syncthreads();

        // row -> local group: branch-free binary search over csrl[0..ng]
        const int rs = min(r0c + lane, p1 - 1);
        int lo = 0, hi = ng;
#pragma unroll
        for (int it = 0; it < 5; ++it) {   // ng <= 32 -> width 1 after 5 steps
            int mid = (lo + hi) >> 1;
            bool c = (csrl[mid] <= rs);
            lo = c ? mid : lo;
            hi = c ? hi : mid;
        }

        float acc[16];
#pragma unroll
        for (int j = 0; j < 16; ++j) acc[j] = biasL[lo * 65 + jb + j];

        // GEMV1: acc[j] += x[row][k] * Wsum[k][jb+j]
#pragma unroll 2
        for (int k = 0; k < 64; ++k) {
            float xk = smem[lane * 65 + k];
            const float* __restrict__ wr = wsum + (k << 6) + jb;   // s_load
#pragma unroll
            for (int j = 0; j < 16; ++j) acc[j] = fmaf(xk, wr[j], acc[j]);
        }
        __syncthreads();
#pragma unroll
        for (int j = 0; j < 16; ++j) smem[lane * 65 + jb + j] = leaky(acc[j]);
        __syncthreads();

        // GEMV2
        float acc2[16];
#pragma unroll
        for (int j = 0; j < 16; ++j) acc2[j] = 0.f;
#pragma unroll 2
        for (int k = 0; k < 64; ++k) {
            float yk = smem[lane * 65 + k];
            const float* __restrict__ wr = w2 + (k << 6) + jb;     // s_load
#pragma unroll
            for (int j = 0; j < 16; ++j) acc2[j] = fmaf(yk, wr[j], acc2[j]);
        }
        __syncthreads();
#pragma unroll
        for (int j = 0; j < 16; ++j) smem[lane * 65 + jb + j] = leaky(acc2[j]);
        __syncthreads();

        // coalesced float4 epilogue
        float* o = out + (size_t)r0c * 64;
#pragma unroll
        for (int i = 0; i < 4; ++i) {
            int f = (i * 256 + tid) * 4;
            if (f < availf) {
                int r = f >> 6, c = f & 63;
                *(float4*)(o + f) = make_float4(smem[r * 65 + c], smem[r * 65 + c + 1],
                                                smem[r * 65 + c + 2], smem[r * 65 + c + 3]);
            }
        }
        __syncthreads();  // next chunk's staging overwrites smem
    }
}

// ---------------------------------------------------------------------------
extern "C" void kernel_launch(void* const* d_in, const int* in_sizes, int n_in,
                              void* d_out, int out_size, void* d_ws, size_t ws_size,
                              hipStream_t stream) {
    const float* x   = (const float*)d_in[0];
    const int*   csr = (const int*)d_in[1];
    const float* w1  = (const float*)d_in[2];
    const float* w2  = (const float*)d_in[3];
    float* out  = (float*)d_out;
    float* wsum = (float*)d_ws;   // 4096 floats

    k0_wsum<<<16, 256, 0, stream>>>(w1, wsum);
    const int grid = (NGRP + GPB - 1) / GPB;   // 1563
    fused<<<grid, 256, 0, stream>>>(x, csr, w1, wsum, w2, out);
}

// Round 5
// 295.847 us; speedup vs baseline: 1.3156x; 1.3156x over previous
//
#include <hip/hip_runtime.h>
#include <math.h>

#define NROWS 500000
#define NGRP  50000
#define NEG   0.2f
#define GPB   16          // groups per block (50000/16 = 3125 exactly)

typedef __attribute__((ext_vector_type(8))) short bf16x8;   // 8 bf16 = 4 VGPRs
typedef __attribute__((ext_vector_type(4))) float f32x4;    // MFMA C/D
typedef unsigned int uint32;

__device__ __forceinline__ float leaky(float h) { return h >= 0.f ? h : NEG * h; }
__device__ __forceinline__ unsigned short f2bf(float v) {   // RNE
    uint32 u = __float_as_uint(v);
    u += 0x7FFFu + ((u >> 16) & 1u);
    return (unsigned short)(u >> 16);
}

// ---------------------------------------------------------------------------
// K0: pack Wsum = W1a+W1b+W1c and W2 into bf16 MFMA B-fragment-major layout:
//   frag[((ks*64 + n)*4 + q)*8 + j] = W[ks*32 + q*8 + j][n]
// so a wave's lane (n=lane&15+16w, q=lane>>4) reads its 8 bf16 contiguously
// (16 B) and the whole wave's read is one coalesced 1 KB segment.
__global__ void k0_frag(const float* __restrict__ w1, const float* __restrict__ w2,
                        unsigned short* __restrict__ wsf, unsigned short* __restrict__ w2f) {
    int r = blockIdx.x * 256 + threadIdx.x;
    if (r >= 4096) return;
    int j = r & 7, q = (r >> 3) & 3, n = (r >> 5) & 63, ks = r >> 11;
    int k = ks * 32 + q * 8 + j;
    float ws = w1[k * 64 + n] + w1[4096 + k * 64 + n] + w1[8192 + k * 64 + n];
    wsf[r] = f2bf(ws);
    w2f[r] = f2bf(w2[k * 64 + n]);
}

// ---------------------------------------------------------------------------
// Fused: block = 16 consecutive CSR groups (~160 rows).
// A1: per-group min/max (fp32) -> LDS.   A2: bias_g = -(mn@W1b+mx@W1c), fp32,
//     s_load weights.   B: 64-row chunks, both layers via mfma_16x16x32_bf16,
//     2 barriers per chunk. Verified layouts: A[m=lane&15][k=q*8+j],
//     C/D[row=q*4+reg][col=lane&15].
__global__ __launch_bounds__(256, 6)
void fused(const float* __restrict__ x, const int* __restrict__ csr,
           const float* __restrict__ w1,
           const unsigned short* __restrict__ wsf,
           const unsigned short* __restrict__ w2f,
           float* __restrict__ out) {
    __shared__ short xb[64 * 72];                 // x chunk, bf16, stride 72 (16B-aligned rows, 2-way banks)
    __shared__ short y1s[64 * 72];                // layer-1 activations bf16; overlaid w/ fp32 mnmx in phase A
    __shared__ float biasL[GPB * 65];
    __shared__ __align__(16) int rowgrpL[64];
    __shared__ int csrl[GPB + 1];

    const int tid = threadIdx.x, w = tid >> 6, lane = tid & 63;
    const int q = lane >> 4, nl = lane & 15;
    const int jb = __builtin_amdgcn_readfirstlane(w * 16);  // SGPR -> s_load weights in A2
    const int n = jb + nl;                                  // this lane's output column

    const int g0 = blockIdx.x * GPB;
    const int ng = min(GPB, NGRP - g0);
    if (tid <= ng) csrl[tid] = csr[g0 + tid];
    __syncthreads();
    const int p0 = csrl[0], p1 = csrl[ng];

    // ---- A1: min/max per group (wave-serial over 4 groups), fp32 into mnF
    float* mnF = (float*)y1s;                     // [GPB][130] fp32 (8320 B <= 9216)
    for (int gl = w; gl < ng; gl += 4) {
        int q0 = csrl[gl], q1 = csrl[gl + 1], cnt = q1 - q0;
        if (cnt > 0) {
            const float* p = x + (size_t)q0 * 64 + lane;
            float mn = INFINITY, mx = -INFINITY;
            int i = 0;
            for (; i + 4 <= cnt; i += 4) {
                float a = p[0], b = p[64], c = p[128], d = p[192];
                p += 256;
                mn = fminf(mn, fminf(fminf(a, b), fminf(c, d)));
                mx = fmaxf(mx, fmaxf(fmaxf(a, b), fmaxf(c, d)));
            }
            for (; i < cnt; ++i) { float a = p[0]; p += 64; mn = fminf(mn, a); mx = fmaxf(mx, a); }
            mnF[gl * 130 + lane]      = mn;
            mnF[gl * 130 + 64 + lane] = mx;
        }
    }
    __syncthreads();

    // ---- A2: bias GEMV (lanes 0..15 = groups), fp32, weights via s_load
    {
        const int gidx = lane < GPB ? lane : 0;
        float acc[16];
#pragma unroll
        for (int j = 0; j < 16; ++j) acc[j] = 0.f;
#pragma unroll 2
        for (int k = 0; k < 128; ++k) {
            float m = mnF[gidx * 130 + k];        // mn (k<64) / mx (k>=64)
            const float* __restrict__ wr = w1 + (64 + k) * 64 + jb;  // s_load
#pragma unroll
            for (int j = 0; j < 16; ++j) acc[j] = fmaf(m, wr[j], acc[j]);
        }
        if (lane < ng) {
#pragma unroll
            for (int j = 0; j < 16; ++j) biasL[lane * 65 + jb + j] = -acc[j];
        }
    }
    __syncthreads();   // bias ready; mnF dead -> y1s reusable

    // ---- B-fragments for both layers: held in VGPRs for the whole block
    const bf16x8* wsv = (const bf16x8*)wsf;
    const bf16x8* w2v = (const bf16x8*)w2f;
    bf16x8 B0 = wsv[n * 4 + q];            // layer1, k = q*8..q*8+7
    bf16x8 B1 = wsv[(64 + n) * 4 + q];     // layer1, k = 32+q*8..
    bf16x8 C0 = w2v[n * 4 + q];            // layer2
    bf16x8 C1 = w2v[(64 + n) * 4 + q];

    // ---- B: 64-row chunks
    const int nch = (p1 - p0 + 63) >> 6;
    for (int ch = 0; ch < nch; ++ch) {
        const int r0c  = p0 + (ch << 6);
        const int rows = min(64, p1 - r0c);
        const int availf = rows * 64;

        // stage x chunk -> bf16 LDS (coalesced float4 reads)
        const float4* x4 = (const float4*)(x + (size_t)r0c * 64);
#pragma unroll
        for (int i = 0; i < 4; ++i) {
            int f = (i * 256 + tid) * 4;
            if (f < availf) {
                float4 v = x4[f >> 2];
                int r = f >> 6, c = f & 63;
                uint32 lo = (uint32)f2bf(v.x) | ((uint32)f2bf(v.y) << 16);
                uint32 hi = (uint32)f2bf(v.z) | ((uint32)f2bf(v.w) << 16);
                *(uint32*)(&xb[r * 72 + c])     = lo;
                *(uint32*)(&xb[r * 72 + c + 2]) = hi;
            }
        }
        // row -> local group (branch-free binary search), once per chunk
        if (tid < 64) {
            int rs = min(r0c + tid, p1 - 1);
            int lo = 0, hi = ng;
#pragma unroll
            for (int it = 0; it < 5; ++it) {
                int mid = (lo + hi) >> 1;
                bool c = csrl[mid] <= rs;
                lo = c ? mid : lo;
                hi = c ? hi : mid;
            }
            rowgrpL[tid] = lo;
        }
        __syncthreads();   // barrier 1: xb + rowgrpL ready

        // layer 1: h = leaky(x @ Wsum + bias[g])
        f32x4 h[4];
#pragma unroll
        for (int mt = 0; mt < 4; ++mt) {
            int rbase = mt * 16 + q * 4;
            int4 grp = *(const int4*)(&rowgrpL[rbase]);   // 4 rows' groups, b128
            f32x4 acc;
            acc.x = biasL[grp.x * 65 + n];
            acc.y = biasL[grp.y * 65 + n];
            acc.z = biasL[grp.z * 65 + n];
            acc.w = biasL[grp.w * 65 + n];
            bf16x8 a0 = *(const bf16x8*)(&xb[(mt * 16 + nl) * 72 + q * 8]);
            bf16x8 a1 = *(const bf16x8*)(&xb[(mt * 16 + nl) * 72 + 32 + q * 8]);
            acc = __builtin_amdgcn_mfma_f32_16x16x32_bf16(a0, B0, acc, 0, 0, 0);
            acc = __builtin_amdgcn_mfma_f32_16x16x32_bf16(a1, B1, acc, 0, 0, 0);
            h[mt] = acc;
        }
        // park leaky(h) as bf16 in y1s (C-layout -> A-layout transpose via LDS)
#pragma unroll
        for (int mt = 0; mt < 4; ++mt) {
            int rbase = mt * 16 + q * 4;
#pragma unroll
            for (int r = 0; r < 4; ++r)
                y1s[(rbase + r) * 72 + n] = (short)f2bf(leaky(h[mt][r]));
        }
        __syncthreads();   // barrier 2: y1 ready; xb reads done

        // layer 2: out = leaky(y1 @ W2), direct C-layout stores (4x64B segs/instr)
#pragma unroll
        for (int mt = 0; mt < 4; ++mt) {
            f32x4 acc = {0.f, 0.f, 0.f, 0.f};
            bf16x8 a0 = *(const bf16x8*)(&y1s[(mt * 16 + nl) * 72 + q * 8]);
            bf16x8 a1 = *(const bf16x8*)(&y1s[(mt * 16 + nl) * 72 + 32 + q * 8]);
            acc = __builtin_amdgcn_mfma_f32_16x16x32_bf16(a0, C0, acc, 0, 0, 0);
            acc = __builtin_amdgcn_mfma_f32_16x16x32_bf16(a1, C1, acc, 0, 0, 0);
            int rbase = mt * 16 + q * 4;
#pragma unroll
            for (int r = 0; r < 4; ++r) {
                int rl = rbase + r;
                if (rl < rows)
                    out[(size_t)(r0c + rl) * 64 + n] = leaky(acc[r]);
            }
        }
        // no 3rd barrier needed: next stage writes xb/rowgrpL only after
        // barrier 1, which requires all waves past layer-2's y1 reads? no --
        // it requires all waves to RE-ENTER staging; a lagging wave still in
        // layer 2 reads only y1s/out, while leaders write only xb/rowgrpL,
        // whose previous-chunk reads completed before barrier 2. Disjoint.
    }
}

// ---------------------------------------------------------------------------
extern "C" void kernel_launch(void* const* d_in, const int* in_sizes, int n_in,
                              void* d_out, int out_size, void* d_ws, size_t ws_size,
                              hipStream_t stream) {
    const float* x   = (const float*)d_in[0];
    const int*   csr = (const int*)d_in[1];
    const float* w1  = (const float*)d_in[2];
    const float* w2  = (const float*)d_in[3];
    float* out = (float*)d_out;

    unsigned short* wsf = (unsigned short*)d_ws;   // 4096 bf16
    unsigned short* w2f = wsf + 4096;              // 4096 bf16

    k0_frag<<<16, 256, 0, stream>>>(w1, w2, wsf, w2f);
    const int grid = (NGRP + GPB - 1) / GPB;       // 3125
    fused<<<grid, 256, 0, stream>>>(x, csr, w1, wsf, w2f, out);
}